// Round 8
// baseline (12063.995 us; speedup 1.0000x reference)
//
#include <hip/hip_runtime.h>
#include <hip/hip_cooperative_groups.h>
#include <math.h>

namespace cg = cooperative_groups;

// Round 8: persistent cooperative kernels. Theory: every kernel boundary on
// multi-XCD forces L2 inv/wb, so each of the 128+72 step launches re-streamed
// ~50-80 MB (weights + replicated h/X) from L3/HBM at latency-bound rates
// (~40-50us/step; r7's intra-kernel wave doubling gave only 9% because the
// cost is the per-launch cold-L2 refill). Fix: enc_all = one cooperative
// kernel looping 128 steps with grid.sync(); dec_all = one cooperative kernel
// looping 24 steps x 3 phases (qk/attn/gates). Blocks stay pinned to CUs ->
// weight slices stay XCD-local. Math/tiling/numerics identical to round 7.

#define NB 128
#define NL 128
#define NH 1024
#define NA 256
#define NT 24
#define NM 151

typedef __attribute__((ext_vector_type(8))) short bf16x8;
typedef __attribute__((ext_vector_type(8))) short s16x8;
typedef __attribute__((ext_vector_type(4))) float f32x4;

#define MFMA(a, b, acc) __builtin_amdgcn_mfma_f32_16x16x32_bf16(a, b, acc, 0, 0, 0)

#define I16_SCALE 32767.0f
#define I16_INV   (1.0f / 32767.0f)

__device__ __forceinline__ float sig_f(float x) {
  return 1.0f / (1.0f + __expf(-x));
}
__device__ __forceinline__ float tanh_f(float x) {
  x = fminf(9.0f, fmaxf(-9.0f, x));
  float e = __expf(2.0f * x);
  return (e - 1.0f) / (e + 1.0f);
}
__device__ __forceinline__ unsigned short f2bf(float f) {
  unsigned int u = __float_as_uint(f);
  u = (u + 0x7FFFu + ((u >> 16) & 1u)) >> 16;
  return (unsigned short)u;
}
__device__ __forceinline__ float bf2f(unsigned short u) {
  return __uint_as_float(((unsigned int)u) << 16);
}
__device__ __forceinline__ short f2i16(float f) {
  return (short)__float2int_rn(f * I16_SCALE);
}

// ---------------------------------------------------------------------------
// conv front (proven round 1)
// ---------------------------------------------------------------------------
__global__ __launch_bounds__(128) void conv_front(
    const float* __restrict__ x,
    const float* __restrict__ w1, const float* __restrict__ b1,
    const float* __restrict__ w2, const float* __restrict__ b2,
    const float* __restrict__ w3, const float* __restrict__ b3,
    float* __restrict__ lstm_in)
{
  int b = blockIdx.x;
  int t = threadIdx.x;
  __shared__ float d[128][36];
  __shared__ float h1[128][34];
  __shared__ float h2[128][32];

  const float* xr = x + (size_t)(b * NL + t) * 48;
  #pragma unroll
  for (int f = 0; f < 36; ++f) d[t][f] = xr[f];
  __syncthreads();

  float acc[34];
  {
    float bias = b1[t];
    #pragma unroll
    for (int w = 0; w < 34; ++w) acc[w] = bias;
  }
  const float* wr = w1 + t * 384;
  for (int ci = 0; ci < 128; ++ci) {
    float row[36];
    #pragma unroll
    for (int f = 0; f < 36; ++f) row[f] = d[ci][f];
    float wa = wr[ci * 3 + 0], wb = wr[ci * 3 + 1], wc = wr[ci * 3 + 2];
    #pragma unroll
    for (int w = 0; w < 34; ++w)
      acc[w] += row[w] * wa + row[w + 1] * wb + row[w + 2] * wc;
  }
  #pragma unroll
  for (int w = 0; w < 34; ++w) {
    float z = acc[w];
    h1[t][w] = (z > 20.0f) ? z : log1pf(__expf(z));
  }
  __syncthreads();

  float acc2[32];
  {
    float bias = b2[t];
    #pragma unroll
    for (int w = 0; w < 32; ++w) acc2[w] = bias;
  }
  const float* wr2 = w2 + t * 384;
  for (int ci = 0; ci < 128; ++ci) {
    float row[34];
    #pragma unroll
    for (int f = 0; f < 34; ++f) row[f] = h1[ci][f];
    float wa = wr2[ci * 3 + 0], wb = wr2[ci * 3 + 1], wc = wr2[ci * 3 + 2];
    #pragma unroll
    for (int w = 0; w < 32; ++w)
      acc2[w] += row[w] * wa + row[w + 1] * wb + row[w + 2] * wc;
  }
  #pragma unroll
  for (int w = 0; w < 32; ++w) h2[t][w] = fmaxf(acc2[w], 0.0f);
  __syncthreads();

  float* outr = lstm_in + (size_t)(b * NL + t) * 18;
  #pragma unroll
  for (int e = 0; e < 6; ++e) {
    float s = b3[e];
    #pragma unroll
    for (int f = 0; f < 32; ++f) s += h2[t][f] * w3[e * 32 + f];
    outr[e] = s;
  }
  #pragma unroll
  for (int j = 0; j < 12; ++j) outr[6 + j] = xr[36 + j];
}

// ---------------------------------------------------------------------------
// conversion / init
// ---------------------------------------------------------------------------
__global__ void split_bf(const float* __restrict__ src,
                         unsigned short* __restrict__ hi,
                         unsigned short* __restrict__ lo, int n) {
  int i = blockIdx.x * 256 + threadIdx.x;
  if (i < n) {
    float v = src[i];
    unsigned short h = f2bf(v);
    hi[i] = h;
    lo[i] = f2bf(v - bf2f(h));
  }
}

__global__ void build_xs(const float* __restrict__ lstm_in,
                         unsigned short* __restrict__ hi,
                         unsigned short* __restrict__ lo) {
  int i = blockIdx.x * 256 + threadIdx.x;
  if (i >= NB * NL * 32) return;
  int b = i >> 12;
  int rem = i & 4095;
  int t = rem >> 5;
  int f = rem & 31;
  float v = (f < 18) ? lstm_in[(size_t)(b * NL + t) * 18 + f] : 0.0f;
  unsigned short h = f2bf(v);
  hi[i] = h;
  lo[i] = f2bf(v - bf2f(h));
}

__global__ void build_wx(const float* __restrict__ wih,
                         unsigned short* __restrict__ hi,
                         unsigned short* __restrict__ lo) {
  int i = blockIdx.x * 256 + threadIdx.x;
  if (i >= 4096 * 32) return;
  int row = i >> 5;
  int f = i & 31;
  float v = (f < 18) ? wih[(size_t)row * 18 + f] : 0.0f;
  unsigned short h = f2bf(v);
  hi[i] = h;
  lo[i] = f2bf(v - bf2f(h));
}

__global__ void init_all(float* __restrict__ c,
                         unsigned short* __restrict__ hhi0,
                         unsigned short* __restrict__ hlo0,
                         float* __restrict__ out) {
  int i = blockIdx.x * 256 + threadIdx.x;
  if (i < NB * NH) { c[i] = 0.0f; hhi0[i] = 0; hlo0[i] = 0; }
  if (i < NB * NT) out[i] = 0.0f;
}

// ---------------------------------------------------------------------------
// Persistent encoder: 128 blocks x 512 threads, loops t=0..127, grid.sync
// per step. Body identical to r7 enc_step.
// ---------------------------------------------------------------------------
struct EncArgs {
  unsigned short* hhi0; unsigned short* hlo0;
  unsigned short* hhi1; unsigned short* hlo1;
  const unsigned short* Whh_hi; const unsigned short* Whh_lo;
  const unsigned short* Wx_hi;  const unsigned short* Wx_lo;
  const unsigned short* xs_hi;  const unsigned short* xs_lo;
  const float* encb;
  float* c;
  short* buf;
};

__global__ __launch_bounds__(512) void enc_all(EncArgs a) {
  cg::grid_group grid = cg::this_grid();
  __shared__ float G[2][128][33];
  int tid = threadIdx.x;
  int w8 = tid >> 6, lane = tid & 63;
  int grp = w8 >> 2, wm = w8 & 3;
  int l15 = lane & 15, q8 = (lane >> 4) * 8, q4 = (lane >> 4) * 4;
  int c0 = blockIdx.x * 8;

  size_t r0 = (size_t)((l15 >> 3) * NH + c0 + (l15 & 7));
  size_t r1 = (size_t)(((l15 >> 3) + 2) * NH + c0 + (l15 & 7));
  const unsigned short* B0h = a.Whh_hi + r0 * NH;
  const unsigned short* B1h = a.Whh_hi + r1 * NH;
  const unsigned short* B0l = a.Whh_lo + r0 * NH;
  const unsigned short* B1l = a.Whh_lo + r1 * NH;
  size_t ar0 = (size_t)(32 * wm + l15) * NH;
  size_t ar1 = (size_t)(32 * wm + 16 + l15) * NH;
  int kbase = grp * 512;

  for (int t = 0; t < NL; ++t) {
    const unsigned short* hhi_in = (t & 1) ? a.hhi1 : a.hhi0;
    const unsigned short* hlo_in = (t & 1) ? a.hlo1 : a.hlo0;
    unsigned short* hhi_out = (t & 1) ? a.hhi0 : a.hhi1;
    unsigned short* hlo_out = (t & 1) ? a.hlo0 : a.hlo1;
    const unsigned short* A0h = hhi_in + ar0;
    const unsigned short* A1h = hhi_in + ar1;
    const unsigned short* A0l = hlo_in + ar0;
    const unsigned short* A1l = hlo_in + ar1;

    f32x4 a00 = {0,0,0,0}, a01 = {0,0,0,0}, a10 = {0,0,0,0}, a11 = {0,0,0,0};
    for (int k0 = 0; k0 < 512; k0 += 32) {
      int ko = kbase + k0 + q8;
      bf16x8 x0h = *(const bf16x8*)(A0h + ko);
      bf16x8 x0l = *(const bf16x8*)(A0l + ko);
      bf16x8 x1h = *(const bf16x8*)(A1h + ko);
      bf16x8 x1l = *(const bf16x8*)(A1l + ko);
      bf16x8 y0h = *(const bf16x8*)(B0h + ko);
      bf16x8 y0l = *(const bf16x8*)(B0l + ko);
      bf16x8 y1h = *(const bf16x8*)(B1h + ko);
      bf16x8 y1l = *(const bf16x8*)(B1l + ko);
      a00 = MFMA(x0h, y0h, a00); a00 = MFMA(x0l, y0h, a00); a00 = MFMA(x0h, y0l, a00);
      a01 = MFMA(x0h, y1h, a01); a01 = MFMA(x0l, y1h, a01); a01 = MFMA(x0h, y1l, a01);
      a10 = MFMA(x1h, y0h, a10); a10 = MFMA(x1l, y0h, a10); a10 = MFMA(x1h, y0l, a10);
      a11 = MFMA(x1h, y1h, a11); a11 = MFMA(x1l, y1h, a11); a11 = MFMA(x1h, y1l, a11);
    }
    if (grp == 0) {
      size_t xo0 = (size_t)(32 * wm + l15) * 4096 + t * 32 + q8;
      size_t xo1 = (size_t)(32 * wm + 16 + l15) * 4096 + t * 32 + q8;
      bf16x8 x0h = *(const bf16x8*)(a.xs_hi + xo0);
      bf16x8 x0l = *(const bf16x8*)(a.xs_lo + xo0);
      bf16x8 x1h = *(const bf16x8*)(a.xs_hi + xo1);
      bf16x8 x1l = *(const bf16x8*)(a.xs_lo + xo1);
      bf16x8 y0h = *(const bf16x8*)(a.Wx_hi + r0 * 32 + q8);
      bf16x8 y0l = *(const bf16x8*)(a.Wx_lo + r0 * 32 + q8);
      bf16x8 y1h = *(const bf16x8*)(a.Wx_hi + r1 * 32 + q8);
      bf16x8 y1l = *(const bf16x8*)(a.Wx_lo + r1 * 32 + q8);
      a00 = MFMA(x0h, y0h, a00); a00 = MFMA(x0l, y0h, a00); a00 = MFMA(x0h, y0l, a00);
      a01 = MFMA(x0h, y1h, a01); a01 = MFMA(x0l, y1h, a01); a01 = MFMA(x0h, y1l, a01);
      a10 = MFMA(x1h, y0h, a10); a10 = MFMA(x1l, y0h, a10); a10 = MFMA(x1h, y0l, a10);
      a11 = MFMA(x1h, y1h, a11); a11 = MFMA(x1l, y1h, a11); a11 = MFMA(x1h, y1l, a11);
    }
    #pragma unroll
    for (int r = 0; r < 4; ++r) {
      G[grp][32 * wm + q4 + r][l15]           = a00[r];
      G[grp][32 * wm + q4 + r][16 + l15]      = a01[r];
      G[grp][32 * wm + 16 + q4 + r][l15]      = a10[r];
      G[grp][32 * wm + 16 + q4 + r][16 + l15] = a11[r];
    }
    __syncthreads();

    if (tid < 256) {
      int b = tid >> 1;
      int cc0 = (tid & 1) * 4;
      float4 cold = *(const float4*)(a.c + (size_t)b * NH + c0 + cc0);
      float rc[4], rh[4];
      #pragma unroll
      for (int j = 0; j < 4; ++j) {
        int cc = cc0 + j;
        float gate[4];
        #pragma unroll
        for (int q = 0; q < 4; ++q) {
          int gi = q * 8 + cc;
          gate[q] = G[0][b][gi] + G[1][b][gi] + a.encb[q * NH + c0 + cc];
        }
        float co = (&cold.x)[j];
        float cn = sig_f(gate[1]) * co + sig_f(gate[0]) * tanh_f(gate[2]);
        float hn = sig_f(gate[3]) * tanh_f(cn);
        rc[j] = cn; rh[j] = hn;
      }
      *(float4*)(a.c + (size_t)b * NH + c0 + cc0) =
          make_float4(rc[0], rc[1], rc[2], rc[3]);
      unsigned short hh[4], hl[4];
      short hq[4];
      #pragma unroll
      for (int j = 0; j < 4; ++j) {
        hh[j] = f2bf(rh[j]);
        hl[j] = f2bf(rh[j] - bf2f(hh[j]));
        hq[j] = f2i16(rh[j]);
      }
      size_t hoff = (size_t)b * NH + c0 + cc0;
      *(ushort4*)(hhi_out + hoff) = make_ushort4(hh[0], hh[1], hh[2], hh[3]);
      *(ushort4*)(hlo_out + hoff) = make_ushort4(hl[0], hl[1], hl[2], hl[3]);
      *(short4*)(a.buf + (size_t)(b * NM + t) * NH + c0 + cc0) =
          make_short4(hq[0], hq[1], hq[2], hq[3]);
    }
    grid.sync();
  }
}

// ---------------------------------------------------------------------------
// dec_prep: h from dedicated hi/lo buffers, c fp32 -> q rows.
// ---------------------------------------------------------------------------
__global__ __launch_bounds__(256) void dec_prep(
    const unsigned short* __restrict__ hhi,
    const unsigned short* __restrict__ hlo,
    const float* __restrict__ c,
    unsigned short* __restrict__ qhi, unsigned short* __restrict__ qlo)
{
  int b = blockIdx.x;
  int j = threadIdx.x * 4;
  ushort4 hv = *(const ushort4*)(hhi + (size_t)b * NH + j);
  ushort4 lv = *(const ushort4*)(hlo + (size_t)b * NH + j);
  float4 cv = *(const float4*)(c + (size_t)b * NH + j);
  unsigned short ch[4], cl[4];
  float cf[4] = {cv.x, cv.y, cv.z, cv.w};
  #pragma unroll
  for (int k = 0; k < 4; ++k) {
    ch[k] = f2bf(cf[k]); cl[k] = f2bf(cf[k] - bf2f(ch[k]));
  }
  *(ushort4*)(qhi + (size_t)(2 * b) * NH + j) = hv;
  *(ushort4*)(qlo + (size_t)(2 * b) * NH + j) = lv;
  *(ushort4*)(qhi + (size_t)(2 * b + 1) * NH + j) = make_ushort4(ch[0], ch[1], ch[2], ch[3]);
  *(ushort4*)(qlo + (size_t)(2 * b + 1) * NH + j) = make_ushort4(cl[0], cl[1], cl[2], cl[3]);
}

// ---------------------------------------------------------------------------
// Bulk kp: kp = buf(i16) @ Wk^T (2-term). grid(302,4).
// ---------------------------------------------------------------------------
__global__ __launch_bounds__(256) void gemm_kp(
    const short* __restrict__ A,
    const unsigned short* __restrict__ Bhi,
    const unsigned short* __restrict__ Blo,
    unsigned short* __restrict__ C)
{
  int tid = threadIdx.x;
  int w = tid >> 6, lane = tid & 63;
  int l15 = lane & 15, q8 = (lane >> 4) * 8, q4 = (lane >> 4) * 4;
  size_t m0 = (size_t)blockIdx.x * 64;
  int n0 = blockIdx.y * 64 + w * 16;

  const unsigned short* Bh = Bhi + (size_t)(n0 + l15) * NH;
  const unsigned short* Bl = Blo + (size_t)(n0 + l15) * NH;
  f32x4 acc[4] = {{0,0,0,0},{0,0,0,0},{0,0,0,0},{0,0,0,0}};
  for (int k0 = 0; k0 < NH; k0 += 32) {
    int ko = k0 + q8;
    bf16x8 bh = *(const bf16x8*)(Bh + ko);
    bf16x8 bl = *(const bf16x8*)(Bl + ko);
    #pragma unroll
    for (int i = 0; i < 4; ++i) {
      s16x8 av = *(const s16x8*)(A + (m0 + 16 * i + l15) * (size_t)NH + ko);
      bf16x8 ah;
      #pragma unroll
      for (int k = 0; k < 8; ++k)
        ah[k] = (short)f2bf((float)av[k] * I16_INV);
      acc[i] = MFMA(ah, bh, acc[i]);
      acc[i] = MFMA(ah, bl, acc[i]);
    }
  }
  #pragma unroll
  for (int i = 0; i < 4; ++i)
    #pragma unroll
    for (int r = 0; r < 4; ++r)
      C[(m0 + 16 * i + q4 + r) * NA + n0 + l15] = f2bf(acc[i][r]);
}

// ---------------------------------------------------------------------------
// Persistent decoder: 128 blocks x 512 threads; 24 steps x {qk, attn, gates}
// with grid.sync between phases. Bodies identical to r7's three kernels.
// ---------------------------------------------------------------------------
struct DecArgs {
  unsigned short* qA_hi; unsigned short* qA_lo;
  unsigned short* qB_hi; unsigned short* qB_lo;
  const unsigned short* Wqk_hi; const unsigned short* Wqk_lo;
  const unsigned short* Wdx_hi; const unsigned short* Wdx_lo;
  const unsigned short* Wdh_hi; const unsigned short* Wdh_lo;
  float* qkout;
  unsigned short* kp;
  short* buf;
  unsigned short* Xc_hi; unsigned short* Xc_lo;
  const float* Wv;
  const float* decb;
  float* c;
  const float* out_w; const float* out_b;
  float* out;
};

__global__ __launch_bounds__(512) void dec_all(DecArgs a) {
  cg::grid_group grid = cg::this_grid();
  __shared__ float G[2][128][33];
  __shared__ float sWv[256], q0s[256], q1s[256], kNew[256];
  __shared__ float sc[2][NM + 1];
  __shared__ float w0s[NM + 1], w1s[NM + 1];

  int tid = threadIdx.x;
  int w8 = tid >> 6, lane = tid & 63;
  int grp = w8 >> 2, wm = w8 & 3;
  int l15 = lane & 15, q8 = (lane >> 4) * 8, q4 = (lane >> 4) * 4;
  int c0 = blockIdx.x * 8;
  int bb = blockIdx.x;

  size_t r0 = (size_t)((l15 >> 3) * NH + c0 + (l15 & 7));
  size_t r1 = (size_t)(((l15 >> 3) + 2) * NH + c0 + (l15 & 7));

  if (tid < 256) sWv[tid] = a.Wv[tid];

  for (int t = 0; t < NT; ++t) {
    const unsigned short* qih = (t & 1) ? a.qB_hi : a.qA_hi;
    const unsigned short* qil = (t & 1) ? a.qB_lo : a.qA_lo;
    unsigned short* qoh = (t & 1) ? a.qA_hi : a.qB_hi;
    unsigned short* qol = (t & 1) ? a.qA_lo : a.qB_lo;

    // ---- phase 1: qk projections (wave tiles 16x16, 512 tiles) ----
    {
      int tileId = bb * 8 + w8;
      if (tileId < 512) {
        int m0 = (tileId >> 5) * 16;
        int n0 = (tileId & 31) * 16;
        const unsigned short* Ah = qih + (size_t)(m0 + l15) * NH;
        const unsigned short* Al = qil + (size_t)(m0 + l15) * NH;
        const unsigned short* Bh = a.Wqk_hi + (size_t)(n0 + l15) * NH;
        const unsigned short* Bl = a.Wqk_lo + (size_t)(n0 + l15) * NH;
        f32x4 acc = {0, 0, 0, 0};
        for (int k0 = 0; k0 < NH; k0 += 32) {
          int ko = k0 + q8;
          bf16x8 ah = *(const bf16x8*)(Ah + ko);
          bf16x8 al = *(const bf16x8*)(Al + ko);
          bf16x8 bh = *(const bf16x8*)(Bh + ko);
          bf16x8 bl = *(const bf16x8*)(Bl + ko);
          acc = MFMA(ah, bh, acc);
          acc = MFMA(al, bh, acc);
          acc = MFMA(ah, bl, acc);
        }
        #pragma unroll
        for (int r = 0; r < 4; ++r)
          a.qkout[(size_t)(m0 + q4 + r) * 512 + n0 + l15] = acc[r];
      }
    }
    grid.sync();

    // ---- phase 2: attention for batch bb ----
    {
      int Mt = NL + t;
      if (tid < 256) {
        q0s[tid] = a.qkout[(size_t)(2 * bb) * 512 + tid];
        q1s[tid] = a.qkout[(size_t)(2 * bb + 1) * 512 + tid];
        float kn = a.qkout[(size_t)(2 * bb) * 512 + 256 + tid];
        kNew[tid] = kn;
        a.kp[((size_t)(bb * NM) + (NL - 1 + t)) * NA + tid] = f2bf(kn);
      }
      __syncthreads();
      for (int idx = tid; idx < 2 * Mt; idx += 512) {
        int m = idx >> 1, n = idx & 1;
        const float* q = n ? q1s : q0s;
        float s = 0.0f;
        if (m == Mt - 1) {
          for (int aa = 0; aa < NA; ++aa) s += tanh_f(q[aa] + kNew[aa]) * sWv[aa];
        } else {
          const unsigned short* kpr = a.kp + ((size_t)(bb * NM) + m) * NA;
          for (int aa = 0; aa < NA; aa += 4) {
            ushort4 kv = *(const ushort4*)(kpr + aa);
            s += tanh_f(q[aa + 0] + bf2f(kv.x)) * sWv[aa + 0];
            s += tanh_f(q[aa + 1] + bf2f(kv.y)) * sWv[aa + 1];
            s += tanh_f(q[aa + 2] + bf2f(kv.z)) * sWv[aa + 2];
            s += tanh_f(q[aa + 3] + bf2f(kv.w)) * sWv[aa + 3];
          }
        }
        sc[n][m] = s;
      }
      __syncthreads();
      for (int m = tid; m < Mt; m += 512) {
        float s0 = sc[0][m], s1 = sc[1][m];
        float mx = fmaxf(s0, s1);
        float e0 = __expf(s0 - mx), e1 = __expf(s1 - mx);
        float inv = 1.0f / (e0 + e1);
        w0s[m] = e0 * inv;
        w1s[m] = e1 * inv;
      }
      __syncthreads();
      if (tid < 256) {
        float4 a0 = {0, 0, 0, 0}, a1 = {0, 0, 0, 0};
        const short* bp = a.buf + ((size_t)bb * NM) * NH + tid * 4;
        for (int m = 0; m < Mt; ++m) {
          short4 v = *(const short4*)(bp + (size_t)m * NH);
          float vx = (float)v.x * I16_INV, vy = (float)v.y * I16_INV;
          float vz = (float)v.z * I16_INV, vw = (float)v.w * I16_INV;
          float w0 = w0s[m], w1 = w1s[m];
          a0.x += vx * w0; a0.y += vy * w0; a0.z += vz * w0; a0.w += vw * w0;
          a1.x += vx * w1; a1.y += vy * w1; a1.z += vz * w1; a1.w += vw * w1;
        }
        float v0[4] = {a0.x, a0.y, a0.z, a0.w};
        float v1[4] = {a1.x, a1.y, a1.z, a1.w};
        unsigned short h0[4], l0[4], h1v[4], l1v[4];
        #pragma unroll
        for (int k = 0; k < 4; ++k) {
          h0[k] = f2bf(v0[k]); l0[k] = f2bf(v0[k] - bf2f(h0[k]));
          h1v[k] = f2bf(v1[k]); l1v[k] = f2bf(v1[k] - bf2f(h1v[k]));
        }
        size_t o0 = (size_t)bb * 2048 + tid * 4;
        size_t o1 = o0 + 1024;
        *(ushort4*)(a.Xc_hi + o0) = make_ushort4(h0[0], h0[1], h0[2], h0[3]);
        *(ushort4*)(a.Xc_lo + o0) = make_ushort4(l0[0], l0[1], l0[2], l0[3]);
        *(ushort4*)(a.Xc_hi + o1) = make_ushort4(h1v[0], h1v[1], h1v[2], h1v[3]);
        *(ushort4*)(a.Xc_lo + o1) = make_ushort4(l1v[0], l1v[1], l1v[2], l1v[3]);
      }
    }
    grid.sync();

    // ---- phase 3: decoder gates + cell ----
    {
      f32x4 a00 = {0,0,0,0}, a01 = {0,0,0,0}, a10 = {0,0,0,0}, a11 = {0,0,0,0};
      // ctx part (split 3-term), K-split: grp0=[0,1536), grp1=[1536,2048)+h
      {
        size_t xr0 = (size_t)(32 * wm + l15) * 2048;
        size_t xr1 = (size_t)(32 * wm + 16 + l15) * 2048;
        const unsigned short* X0h = a.Xc_hi + xr0;
        const unsigned short* X1h = a.Xc_hi + xr1;
        const unsigned short* X0l = a.Xc_lo + xr0;
        const unsigned short* X1l = a.Xc_lo + xr1;
        const unsigned short* W0h = a.Wdx_hi + r0 * 2048;
        const unsigned short* W1h = a.Wdx_hi + r1 * 2048;
        const unsigned short* W0l = a.Wdx_lo + r0 * 2048;
        const unsigned short* W1l = a.Wdx_lo + r1 * 2048;
        int kc_lo = grp ? 1536 : 0;
        int kc_hi = grp ? 2048 : 1536;
        for (int k0 = kc_lo; k0 < kc_hi; k0 += 32) {
          int ko = k0 + q8;
          bf16x8 x0h = *(const bf16x8*)(X0h + ko);
          bf16x8 x0l = *(const bf16x8*)(X0l + ko);
          bf16x8 x1h = *(const bf16x8*)(X1h + ko);
          bf16x8 x1l = *(const bf16x8*)(X1l + ko);
          bf16x8 y0h = *(const bf16x8*)(W0h + ko);
          bf16x8 y0l = *(const bf16x8*)(W0l + ko);
          bf16x8 y1h = *(const bf16x8*)(W1h + ko);
          bf16x8 y1l = *(const bf16x8*)(W1l + ko);
          a00 = MFMA(x0h, y0h, a00); a00 = MFMA(x0l, y0h, a00); a00 = MFMA(x0h, y0l, a00);
          a01 = MFMA(x0h, y1h, a01); a01 = MFMA(x0l, y1h, a01); a01 = MFMA(x0h, y1l, a01);
          a10 = MFMA(x1h, y0h, a10); a10 = MFMA(x1l, y0h, a10); a10 = MFMA(x1h, y0l, a10);
          a11 = MFMA(x1h, y1h, a11); a11 = MFMA(x1l, y1h, a11); a11 = MFMA(x1h, y1l, a11);
        }
      }
      if (grp) {
        size_t ar0 = (size_t)(2 * (32 * wm + l15)) * NH;
        size_t ar1 = (size_t)(2 * (32 * wm + 16 + l15)) * NH;
        const unsigned short* A0h = qih + ar0;
        const unsigned short* A1h = qih + ar1;
        const unsigned short* A0l = qil + ar0;
        const unsigned short* A1l = qil + ar1;
        const unsigned short* B0h = a.Wdh_hi + r0 * NH;
        const unsigned short* B1h = a.Wdh_hi + r1 * NH;
        const unsigned short* B0l = a.Wdh_lo + r0 * NH;
        const unsigned short* B1l = a.Wdh_lo + r1 * NH;
        for (int k0 = 0; k0 < NH; k0 += 32) {
          int ko = k0 + q8;
          bf16x8 x0h = *(const bf16x8*)(A0h + ko);
          bf16x8 x0l = *(const bf16x8*)(A0l + ko);
          bf16x8 x1h = *(const bf16x8*)(A1h + ko);
          bf16x8 x1l = *(const bf16x8*)(A1l + ko);
          bf16x8 y0h = *(const bf16x8*)(B0h + ko);
          bf16x8 y0l = *(const bf16x8*)(B0l + ko);
          bf16x8 y1h = *(const bf16x8*)(B1h + ko);
          bf16x8 y1l = *(const bf16x8*)(B1l + ko);
          a00 = MFMA(x0h, y0h, a00); a00 = MFMA(x0l, y0h, a00); a00 = MFMA(x0h, y0l, a00);
          a01 = MFMA(x0h, y1h, a01); a01 = MFMA(x0l, y1h, a01); a01 = MFMA(x0h, y1l, a01);
          a10 = MFMA(x1h, y0h, a10); a10 = MFMA(x1l, y0h, a10); a10 = MFMA(x1h, y0l, a10);
          a11 = MFMA(x1h, y1h, a11); a11 = MFMA(x1l, y1h, a11); a11 = MFMA(x1h, y1l, a11);
        }
      }
      #pragma unroll
      for (int r = 0; r < 4; ++r) {
        G[grp][32 * wm + q4 + r][l15]           = a00[r];
        G[grp][32 * wm + q4 + r][16 + l15]      = a01[r];
        G[grp][32 * wm + 16 + q4 + r][l15]      = a10[r];
        G[grp][32 * wm + 16 + q4 + r][16 + l15] = a11[r];
      }
      __syncthreads();

      if (tid < 256) {
        int b = tid >> 1;
        int cc0 = (tid & 1) * 4;
        float4 cold = *(const float4*)(a.c + (size_t)b * NH + c0 + cc0);
        float rc[4], rh[4];
        #pragma unroll
        for (int j = 0; j < 4; ++j) {
          int cc = cc0 + j;
          float gate[4];
          #pragma unroll
          for (int q = 0; q < 4; ++q) {
            int gi = q * 8 + cc;
            gate[q] = G[0][b][gi] + G[1][b][gi] + a.decb[q * NH + c0 + cc];
          }
          float co = (&cold.x)[j];
          float cn = sig_f(gate[1]) * co + sig_f(gate[0]) * tanh_f(gate[2]);
          float hn = sig_f(gate[3]) * tanh_f(cn);
          rc[j] = cn; rh[j] = hn;
        }
        *(float4*)(a.c + (size_t)b * NH + c0 + cc0) =
            make_float4(rc[0], rc[1], rc[2], rc[3]);

        float py = 0.0f;
        #pragma unroll
        for (int j = 0; j < 4; ++j) py += rh[j] * a.out_w[c0 + cc0 + j];
        if (blockIdx.x == 0 && (tid & 1) == 0) py += a.out_b[0];
        py += __shfl_down(py, 1);
        if ((tid & 1) == 0) atomicAdd(&a.out[b * NT + t], py);

        if (t < NT - 1) {
          unsigned short hh[4], hl[4], ch[4], cl[4];
          short hq[4];
          #pragma unroll
          for (int j = 0; j < 4; ++j) {
            hh[j] = f2bf(rh[j]); hl[j] = f2bf(rh[j] - bf2f(hh[j]));
            ch[j] = f2bf(rc[j]); cl[j] = f2bf(rc[j] - bf2f(ch[j]));
            hq[j] = f2i16(rh[j]);
          }
          *(short4*)(a.buf + (size_t)(b * NM + NL + t) * NH + c0 + cc0) =
              make_short4(hq[0], hq[1], hq[2], hq[3]);
          size_t qh = (size_t)(2 * b) * NH + c0 + cc0;
          size_t qc = (size_t)(2 * b + 1) * NH + c0 + cc0;
          *(ushort4*)(qoh + qh) = make_ushort4(hh[0], hh[1], hh[2], hh[3]);
          *(ushort4*)(qol + qh) = make_ushort4(hl[0], hl[1], hl[2], hl[3]);
          *(ushort4*)(qoh + qc) = make_ushort4(ch[0], ch[1], ch[2], ch[3]);
          *(ushort4*)(qol + qc) = make_ushort4(cl[0], cl[1], cl[2], cl[3]);
        }
      }
    }
    grid.sync();
  }
}

// ---------------------------------------------------------------------------
extern "C" void kernel_launch(void* const* d_in, const int* in_sizes, int n_in,
                              void* d_out, int out_size, void* d_ws, size_t ws_size,
                              hipStream_t stream) {
  const float* x       = (const float*)d_in[0];
  const float* conv1_w = (const float*)d_in[1];
  const float* conv1_b = (const float*)d_in[2];
  const float* conv2_w = (const float*)d_in[3];
  const float* conv2_b = (const float*)d_in[4];
  const float* lin3_w  = (const float*)d_in[5];
  const float* lin3_b  = (const float*)d_in[6];
  const float* enc_Wih = (const float*)d_in[7];
  const float* enc_Whh = (const float*)d_in[8];
  const float* enc_b   = (const float*)d_in[9];
  const float* attn_Wq = (const float*)d_in[10];
  const float* attn_Wk = (const float*)d_in[11];
  const float* attn_Wv = (const float*)d_in[12];
  const float* dec_Wih = (const float*)d_in[13];
  const float* dec_Whh = (const float*)d_in[14];
  const float* dec_b   = (const float*)d_in[15];
  const float* out_w   = (const float*)d_in[16];
  const float* out_b   = (const float*)d_in[17];
  float* out = (float*)d_out;

  // ---- workspace carve: 106,102,784 B (byte-identical to rounds 6/7) ----
  unsigned short* W = (unsigned short*)d_ws;
  short*          buf    = (short*)W;                  // 19,791,872 i16
  unsigned short* kp     = W + (size_t)19791872;       // 4,947,968
  unsigned short* qA_hi  = kp + 4947968;               // 262,144
  unsigned short* qA_lo  = qA_hi + 262144;
  unsigned short* qB_hi  = qA_lo + 262144;
  unsigned short* qB_lo  = qB_hi + 262144;
  unsigned short* Xc_hi  = qB_lo + 262144;             // 262,144
  unsigned short* Xc_lo  = Xc_hi + 262144;
  unsigned short* Wqk_hi = Xc_lo + 262144;             // 524,288
  unsigned short* Wqk_lo = Wqk_hi + 524288;
  unsigned short* Wdh_hi = Wqk_lo + 524288;            // 4,194,304 (enc Whh first)
  unsigned short* Wdh_lo = Wdh_hi + 4194304;
  unsigned short* Wdx_hi = Wdh_lo + 4194304;           // 8,388,608
  unsigned short* Wdx_lo = Wdx_hi + 8388608;           // 8,388,608
  float* c     = (float*)(Wdx_lo + 8388608);           // 131,072 f
  float* qkout = c + 131072;                           // 131,072 f
  // encoder-phase overlays in Wdx regions (dead until dec weight split):
  unsigned short* h_hi0 = Wdx_hi;                      // 131,072
  unsigned short* h_hi1 = Wdx_hi + 131072;
  unsigned short* h_lo0 = Wdx_hi + 262144;
  unsigned short* h_lo1 = Wdx_hi + 393216;
  unsigned short* xs_hi = Wdx_hi + 524288;             // 524,288
  unsigned short* xs_lo = xs_hi + 524288;              // 524,288
  unsigned short* Wx_hi = xs_lo + 524288;              // 131,072
  unsigned short* Wx_lo = Wx_hi + 131072;              // 131,072
  float* lstm_in = (float*)Wdx_lo;                     // 294,912 f

  init_all<<<512, 256, 0, stream>>>(c, h_hi0, h_lo0, out);
  conv_front<<<NB, 128, 0, stream>>>(x, conv1_w, conv1_b, conv2_w, conv2_b,
                                     lin3_w, lin3_b, lstm_in);
  build_xs<<<2048, 256, 0, stream>>>(lstm_in, xs_hi, xs_lo);
  build_wx<<<512, 256, 0, stream>>>(enc_Wih, Wx_hi, Wx_lo);
  split_bf<<<16384, 256, 0, stream>>>(enc_Whh, Wdh_hi, Wdh_lo, 4194304);
  split_bf<<<1024, 256, 0, stream>>>(attn_Wq, Wqk_hi, Wqk_lo, 262144);
  split_bf<<<1024, 256, 0, stream>>>(attn_Wk, Wqk_hi + 262144, Wqk_lo + 262144, 262144);

  // Persistent encoder: one cooperative launch for all 128 steps
  EncArgs ea;
  ea.hhi0 = h_hi0; ea.hlo0 = h_lo0; ea.hhi1 = h_hi1; ea.hlo1 = h_lo1;
  ea.Whh_hi = Wdh_hi; ea.Whh_lo = Wdh_lo;
  ea.Wx_hi = Wx_hi; ea.Wx_lo = Wx_lo;
  ea.xs_hi = xs_hi; ea.xs_lo = xs_lo;
  ea.encb = enc_b; ea.c = c; ea.buf = buf;
  void* eargs[] = { &ea };
  hipLaunchCooperativeKernel((void*)enc_all, dim3(128), dim3(512),
                             eargs, 0, stream);
  // t=127 (odd) wrote h_hi0/h_lo0 -> final h there

  dec_prep<<<NB, 256, 0, stream>>>(h_hi0, h_lo0, c, qA_hi, qA_lo);
  gemm_kp<<<dim3(302, 4), 256, 0, stream>>>(buf, Wqk_hi + 262144,
                                            Wqk_lo + 262144, kp);

  // decoder weights (overwrite encoder overlays — encoder + dec_prep done)
  split_bf<<<32768, 256, 0, stream>>>(dec_Wih, Wdx_hi, Wdx_lo, 8388608);
  split_bf<<<16384, 256, 0, stream>>>(dec_Whh, Wdh_hi, Wdh_lo, 4194304);

  // Persistent decoder: one cooperative launch for all 24 steps
  DecArgs da;
  da.qA_hi = qA_hi; da.qA_lo = qA_lo; da.qB_hi = qB_hi; da.qB_lo = qB_lo;
  da.Wqk_hi = Wqk_hi; da.Wqk_lo = Wqk_lo;
  da.Wdx_hi = Wdx_hi; da.Wdx_lo = Wdx_lo;
  da.Wdh_hi = Wdh_hi; da.Wdh_lo = Wdh_lo;
  da.qkout = qkout; da.kp = kp; da.buf = buf;
  da.Xc_hi = Xc_hi; da.Xc_lo = Xc_lo;
  da.Wv = attn_Wv; da.decb = dec_b; da.c = c;
  da.out_w = out_w; da.out_b = out_b; da.out = out;
  void* dargs[] = { &da };
  hipLaunchCooperativeKernel((void*)dec_all, dim3(128), dim3(512),
                             dargs, 0, stream);
}

// Round 9
// 4687.420 us; speedup vs baseline: 2.5737x; 2.5737x over previous
//
#include <hip/hip_runtime.h>
#include <math.h>

// Round 9: FRAGMENT-ORDERED operand layouts. r8 counters showed step kernels
// at 48us with MFMA 2.7%/VALU 1.7%/HBM 1.4% -- stalled on ~16K uncoalesced
// 64B transactions per block-step (every operand load was per-lane
// row-strided). Fix: store all MFMA operands in [.. ki][lane][8] fragment
// order so every load is base + lane*16B (1KB/wave coalesced, 16x fewer
// transactions). Weights transformed once; activations written in frag order
// by producers. Per-step launches (cooperative was slower). Math bit-identical
// to round 6/7 (absmax 0.0078).

#define NB 128
#define NL 128
#define NH 1024
#define NA 256
#define NT 24
#define NM 151

typedef __attribute__((ext_vector_type(8))) short bf16x8;
typedef __attribute__((ext_vector_type(8))) short s16x8;
typedef __attribute__((ext_vector_type(4))) float f32x4;

#define MFMA(a, b, acc) __builtin_amdgcn_mfma_f32_16x16x32_bf16(a, b, acc, 0, 0, 0)

#define I16_SCALE 32767.0f
#define I16_INV   (1.0f / 32767.0f)

__device__ __forceinline__ float sig_f(float x) {
  return 1.0f / (1.0f + __expf(-x));
}
__device__ __forceinline__ float tanh_f(float x) {
  x = fminf(9.0f, fmaxf(-9.0f, x));
  float e = __expf(2.0f * x);
  return (e - 1.0f) / (e + 1.0f);
}
__device__ __forceinline__ unsigned short f2bf(float f) {
  unsigned int u = __float_as_uint(f);
  u = (u + 0x7FFFu + ((u >> 16) & 1u)) >> 16;
  return (unsigned short)u;
}
__device__ __forceinline__ float bf2f(unsigned short u) {
  return __uint_as_float(((unsigned int)u) << 16);
}
__device__ __forceinline__ short f2i16(float f) {
  return (short)__float2int_rn(f * I16_SCALE);
}

// ---------------------------------------------------------------------------
// conv front (proven round 1)
// ---------------------------------------------------------------------------
__global__ __launch_bounds__(128) void conv_front(
    const float* __restrict__ x,
    const float* __restrict__ w1, const float* __restrict__ b1,
    const float* __restrict__ w2, const float* __restrict__ b2,
    const float* __restrict__ w3, const float* __restrict__ b3,
    float* __restrict__ lstm_in)
{
  int b = blockIdx.x;
  int t = threadIdx.x;
  __shared__ float d[128][36];
  __shared__ float h1[128][34];
  __shared__ float h2[128][32];

  const float* xr = x + (size_t)(b * NL + t) * 48;
  #pragma unroll
  for (int f = 0; f < 36; ++f) d[t][f] = xr[f];
  __syncthreads();

  float acc[34];
  {
    float bias = b1[t];
    #pragma unroll
    for (int w = 0; w < 34; ++w) acc[w] = bias;
  }
  const float* wr = w1 + t * 384;
  for (int ci = 0; ci < 128; ++ci) {
    float row[36];
    #pragma unroll
    for (int f = 0; f < 36; ++f) row[f] = d[ci][f];
    float wa = wr[ci * 3 + 0], wb = wr[ci * 3 + 1], wc = wr[ci * 3 + 2];
    #pragma unroll
    for (int w = 0; w < 34; ++w)
      acc[w] += row[w] * wa + row[w + 1] * wb + row[w + 2] * wc;
  }
  #pragma unroll
  for (int w = 0; w < 34; ++w) {
    float z = acc[w];
    h1[t][w] = (z > 20.0f) ? z : log1pf(__expf(z));
  }
  __syncthreads();

  float acc2[32];
  {
    float bias = b2[t];
    #pragma unroll
    for (int w = 0; w < 32; ++w) acc2[w] = bias;
  }
  const float* wr2 = w2 + t * 384;
  for (int ci = 0; ci < 128; ++ci) {
    float row[34];
    #pragma unroll
    for (int f = 0; f < 34; ++f) row[f] = h1[ci][f];
    float wa = wr2[ci * 3 + 0], wb = wr2[ci * 3 + 1], wc = wr2[ci * 3 + 2];
    #pragma unroll
    for (int w = 0; w < 32; ++w)
      acc2[w] += row[w] * wa + row[w + 1] * wb + row[w + 2] * wc;
  }
  #pragma unroll
  for (int w = 0; w < 32; ++w) h2[t][w] = fmaxf(acc2[w], 0.0f);
  __syncthreads();

  float* outr = lstm_in + (size_t)(b * NL + t) * 18;
  #pragma unroll
  for (int e = 0; e < 6; ++e) {
    float s = b3[e];
    #pragma unroll
    for (int f = 0; f < 32; ++f) s += h2[t][f] * w3[e * 32 + f];
    outr[e] = s;
  }
  #pragma unroll
  for (int j = 0; j < 12; ++j) outr[6 + j] = xr[36 + j];
}

// ---------------------------------------------------------------------------
// Fragment-order transforms.
// Gate-weight frag (Whh/Wdh/Wdx): entry o = ((bx*2+tile)<<kshift | ki)*64+lane
// holds W[grow][ki*32 + q*8 + j], grow = (idx>>3)*1024 + bx*8 + (idx&7),
// idx = tile*16 + l15.
// ---------------------------------------------------------------------------
__global__ void frag_w(const float* __restrict__ src, int K, int kshift,
                       unsigned short* __restrict__ hi,
                       unsigned short* __restrict__ lo, int ngroups)
{
  int o = blockIdx.x * 256 + threadIdx.x;
  if (o >= ngroups) return;
  int lane = o & 63;
  int ki = (o >> 6) & ((1 << kshift) - 1);
  int tile = (o >> (6 + kshift)) & 1;
  int bx = o >> (7 + kshift);
  int l15 = lane & 15, q = lane >> 4;
  int idx = tile * 16 + l15;
  int grow = (idx >> 3) * 1024 + bx * 8 + (idx & 7);
  const float* s = src + (size_t)grow * K + ki * 32 + q * 8;
  unsigned short hv[8], lv[8];
  #pragma unroll
  for (int j = 0; j < 8; ++j) {
    float v = s[j];
    hv[j] = f2bf(v);
    lv[j] = f2bf(v - bf2f(hv[j]));
  }
  size_t e = (size_t)o * 8;
  *(ushort4*)(hi + e) = make_ushort4(hv[0], hv[1], hv[2], hv[3]);
  *(ushort4*)(hi + e + 4) = make_ushort4(hv[4], hv[5], hv[6], hv[7]);
  *(ushort4*)(lo + e) = make_ushort4(lv[0], lv[1], lv[2], lv[3]);
  *(ushort4*)(lo + e + 4) = make_ushort4(lv[4], lv[5], lv[6], lv[7]);
}

// Wqk frag: entry o = (ntile*32+ki)*64+lane holds row(ntile*16+l15), k.
__global__ void frag_wqk(const float* __restrict__ wq,
                         const float* __restrict__ wk,
                         unsigned short* __restrict__ hi,
                         unsigned short* __restrict__ lo)
{
  int o = blockIdx.x * 256 + threadIdx.x;
  if (o >= 65536) return;
  int lane = o & 63;
  int ki = (o >> 6) & 31;
  int ntile = o >> 11;
  int l15 = lane & 15, q = lane >> 4;
  int row = ntile * 16 + l15;
  int k = ki * 32 + q * 8;
  const float* s = (row < 256) ? (wq + (size_t)row * 1024 + k)
                               : (wk + (size_t)(row - 256) * 1024 + k);
  unsigned short hv[8], lv[8];
  #pragma unroll
  for (int j = 0; j < 8; ++j) {
    float v = s[j];
    hv[j] = f2bf(v);
    lv[j] = f2bf(v - bf2f(hv[j]));
  }
  size_t e = (size_t)o * 8;
  *(ushort4*)(hi + e) = make_ushort4(hv[0], hv[1], hv[2], hv[3]);
  *(ushort4*)(hi + e + 4) = make_ushort4(hv[4], hv[5], hv[6], hv[7]);
  *(ushort4*)(lo + e) = make_ushort4(lv[0], lv[1], lv[2], lv[3]);
  *(ushort4*)(lo + e + 4) = make_ushort4(lv[4], lv[5], lv[6], lv[7]);
}

// Wx frag: entry o = (bx*2+tile)*64+lane holds Wih[grow][q*8+j] (0 pad >=18).
__global__ void frag_wx(const float* __restrict__ wih,
                        unsigned short* __restrict__ hi,
                        unsigned short* __restrict__ lo)
{
  int o = blockIdx.x * 256 + threadIdx.x;
  if (o >= 16384) return;
  int lane = o & 63;
  int tile = (o >> 6) & 1;
  int bx = o >> 7;
  int l15 = lane & 15, q = lane >> 4;
  int idx = tile * 16 + l15;
  int grow = (idx >> 3) * 1024 + bx * 8 + (idx & 7);
  unsigned short hv[8], lv[8];
  #pragma unroll
  for (int j = 0; j < 8; ++j) {
    int k = q * 8 + j;
    float v = (k < 18) ? wih[(size_t)grow * 18 + k] : 0.0f;
    hv[j] = f2bf(v);
    lv[j] = f2bf(v - bf2f(hv[j]));
  }
  size_t e = (size_t)o * 8;
  *(ushort4*)(hi + e) = make_ushort4(hv[0], hv[1], hv[2], hv[3]);
  *(ushort4*)(hi + e + 4) = make_ushort4(hv[4], hv[5], hv[6], hv[7]);
  *(ushort4*)(lo + e) = make_ushort4(lv[0], lv[1], lv[2], lv[3]);
  *(ushort4*)(lo + e + 4) = make_ushort4(lv[4], lv[5], lv[6], lv[7]);
}

// xs frag: entry o = (t*8+btile)*64+lane holds x[b=btile*16+l15][t][q*8+j].
__global__ void frag_xs(const float* __restrict__ lstm_in,
                        unsigned short* __restrict__ hi,
                        unsigned short* __restrict__ lo)
{
  int o = blockIdx.x * 256 + threadIdx.x;
  if (o >= 65536) return;
  int lane = o & 63;
  int btile = (o >> 6) & 7;
  int t = o >> 9;
  int l15 = lane & 15, q = lane >> 4;
  int b = btile * 16 + l15;
  unsigned short hv[8], lv[8];
  #pragma unroll
  for (int j = 0; j < 8; ++j) {
    int k = q * 8 + j;
    float v = (k < 18) ? lstm_in[(size_t)(b * NL + t) * 18 + k] : 0.0f;
    hv[j] = f2bf(v);
    lv[j] = f2bf(v - bf2f(hv[j]));
  }
  size_t e = (size_t)o * 8;
  *(ushort4*)(hi + e) = make_ushort4(hv[0], hv[1], hv[2], hv[3]);
  *(ushort4*)(hi + e + 4) = make_ushort4(hv[4], hv[5], hv[6], hv[7]);
  *(ushort4*)(lo + e) = make_ushort4(lv[0], lv[1], lv[2], lv[3]);
  *(ushort4*)(lo + e + 4) = make_ushort4(lv[4], lv[5], lv[6], lv[7]);
}

__global__ void init_all(float* __restrict__ c,
                         unsigned short* __restrict__ hhi0,
                         unsigned short* __restrict__ hlo0,
                         float* __restrict__ out) {
  int i = blockIdx.x * 256 + threadIdx.x;
  if (i < NB * NH) { c[i] = 0.0f; hhi0[i] = 0; hlo0[i] = 0; }
  if (i < NB * NT) out[i] = 0.0f;
}

// ---------------------------------------------------------------------------
// Encoder step (frag operands): all loads are base + lane*16B, coalesced.
// 512 threads, K-split across wave-groups, LDS partial-G reduce.
// h state frag: elem ki*4096 + btile*512 + lane*8.
// ---------------------------------------------------------------------------
__global__ __launch_bounds__(512) void enc_step(
    const unsigned short* __restrict__ hfi_hi,
    const unsigned short* __restrict__ hfi_lo,
    unsigned short* __restrict__ hfo_hi,
    unsigned short* __restrict__ hfo_lo,
    const unsigned short* __restrict__ Wf_hi,
    const unsigned short* __restrict__ Wf_lo,
    const unsigned short* __restrict__ Wxf_hi,
    const unsigned short* __restrict__ Wxf_lo,
    const unsigned short* __restrict__ xsf_hi,
    const unsigned short* __restrict__ xsf_lo,
    const float* __restrict__ encb,
    float* __restrict__ c,
    short* __restrict__ buf,
    int t)
{
  __shared__ float G[2][128][33];
  int tid = threadIdx.x;
  int w8 = tid >> 6, lane = tid & 63;
  int grp = w8 >> 2, wm = w8 & 3;
  int l15 = lane & 15, q4 = (lane >> 4) * 4;
  int bx = blockIdx.x;
  int c0 = bx * 8;

  const unsigned short* B0h = Wf_hi + (size_t)(bx * 2 + 0) * 16384 + lane * 8;
  const unsigned short* B1h = Wf_hi + (size_t)(bx * 2 + 1) * 16384 + lane * 8;
  const unsigned short* B0l = Wf_lo + (size_t)(bx * 2 + 0) * 16384 + lane * 8;
  const unsigned short* B1l = Wf_lo + (size_t)(bx * 2 + 1) * 16384 + lane * 8;
  const unsigned short* A0h = hfi_hi + (size_t)(2 * wm) * 512 + lane * 8;
  const unsigned short* A1h = hfi_hi + (size_t)(2 * wm + 1) * 512 + lane * 8;
  const unsigned short* A0l = hfi_lo + (size_t)(2 * wm) * 512 + lane * 8;
  const unsigned short* A1l = hfi_lo + (size_t)(2 * wm + 1) * 512 + lane * 8;

  f32x4 a00 = {0,0,0,0}, a01 = {0,0,0,0}, a10 = {0,0,0,0}, a11 = {0,0,0,0};
  for (int i = 0; i < 16; ++i) {
    int ki = grp * 16 + i;
    size_t ao = (size_t)ki * 4096;
    size_t bo = (size_t)ki * 512;
    bf16x8 x0h = *(const bf16x8*)(A0h + ao);
    bf16x8 x0l = *(const bf16x8*)(A0l + ao);
    bf16x8 x1h = *(const bf16x8*)(A1h + ao);
    bf16x8 x1l = *(const bf16x8*)(A1l + ao);
    bf16x8 y0h = *(const bf16x8*)(B0h + bo);
    bf16x8 y0l = *(const bf16x8*)(B0l + bo);
    bf16x8 y1h = *(const bf16x8*)(B1h + bo);
    bf16x8 y1l = *(const bf16x8*)(B1l + bo);
    a00 = MFMA(x0h, y0h, a00); a00 = MFMA(x0l, y0h, a00); a00 = MFMA(x0h, y0l, a00);
    a01 = MFMA(x0h, y1h, a01); a01 = MFMA(x0l, y1h, a01); a01 = MFMA(x0h, y1l, a01);
    a10 = MFMA(x1h, y0h, a10); a10 = MFMA(x1l, y0h, a10); a10 = MFMA(x1h, y0l, a10);
    a11 = MFMA(x1h, y1h, a11); a11 = MFMA(x1l, y1h, a11); a11 = MFMA(x1h, y1l, a11);
  }
  if (grp == 0) {
    size_t xo0 = ((size_t)t * 8 + 2 * wm) * 512 + lane * 8;
    size_t xo1 = xo0 + 512;
    bf16x8 x0h = *(const bf16x8*)(xsf_hi + xo0);
    bf16x8 x0l = *(const bf16x8*)(xsf_lo + xo0);
    bf16x8 x1h = *(const bf16x8*)(xsf_hi + xo1);
    bf16x8 x1l = *(const bf16x8*)(xsf_lo + xo1);
    size_t wo0 = (size_t)(bx * 2 + 0) * 512 + lane * 8;
    size_t wo1 = (size_t)(bx * 2 + 1) * 512 + lane * 8;
    bf16x8 y0h = *(const bf16x8*)(Wxf_hi + wo0);
    bf16x8 y0l = *(const bf16x8*)(Wxf_lo + wo0);
    bf16x8 y1h = *(const bf16x8*)(Wxf_hi + wo1);
    bf16x8 y1l = *(const bf16x8*)(Wxf_lo + wo1);
    a00 = MFMA(x0h, y0h, a00); a00 = MFMA(x0l, y0h, a00); a00 = MFMA(x0h, y0l, a00);
    a01 = MFMA(x0h, y1h, a01); a01 = MFMA(x0l, y1h, a01); a01 = MFMA(x0h, y1l, a01);
    a10 = MFMA(x1h, y0h, a10); a10 = MFMA(x1l, y0h, a10); a10 = MFMA(x1h, y0l, a10);
    a11 = MFMA(x1h, y1h, a11); a11 = MFMA(x1l, y1h, a11); a11 = MFMA(x1h, y1l, a11);
  }
  #pragma unroll
  for (int r = 0; r < 4; ++r) {
    G[grp][32 * wm + q4 + r][l15]           = a00[r];
    G[grp][32 * wm + q4 + r][16 + l15]      = a01[r];
    G[grp][32 * wm + 16 + q4 + r][l15]      = a10[r];
    G[grp][32 * wm + 16 + q4 + r][16 + l15] = a11[r];
  }
  __syncthreads();

  if (tid < 256) {
    int b = tid >> 1;
    int kc = c0 + (tid & 1) * 4;          // absolute gate column base
    int cc0 = (tid & 1) * 4;
    float4 cold = *(const float4*)(c + (size_t)b * NH + kc);
    float rc[4], rh[4];
    #pragma unroll
    for (int j = 0; j < 4; ++j) {
      int cc = cc0 + j;
      float gate[4];
      #pragma unroll
      for (int q = 0; q < 4; ++q) {
        int gi = q * 8 + cc;
        gate[q] = G[0][b][gi] + G[1][b][gi] + encb[q * NH + kc + j];
      }
      float co = (&cold.x)[j];
      float cn = sig_f(gate[1]) * co + sig_f(gate[0]) * tanh_f(gate[2]);
      float hn = sig_f(gate[3]) * tanh_f(cn);
      rc[j] = cn; rh[j] = hn;
    }
    *(float4*)(c + (size_t)b * NH + kc) = make_float4(rc[0], rc[1], rc[2], rc[3]);
    unsigned short hh[4], hl[4];
    short hq[4];
    #pragma unroll
    for (int j = 0; j < 4; ++j) {
      hh[j] = f2bf(rh[j]);
      hl[j] = f2bf(rh[j] - bf2f(hh[j]));
      hq[j] = f2i16(rh[j]);
    }
    // h frag write: ki*4096 + btile*512 + lane'*8 + j8
    int ki = kc >> 5, qq = (kc >> 3) & 3, j8 = kc & 7;
    size_t fo = (size_t)ki * 4096 + (b >> 4) * 512 + ((b & 15) + 16 * qq) * 8 + j8;
    *(ushort4*)(hfo_hi + fo) = make_ushort4(hh[0], hh[1], hh[2], hh[3]);
    *(ushort4*)(hfo_lo + fo) = make_ushort4(hl[0], hl[1], hl[2], hl[3]);
    *(short4*)(buf + (size_t)(b * NM + t) * NH + kc) =
        make_short4(hq[0], hq[1], hq[2], hq[3]);
  }
}

// ---------------------------------------------------------------------------
// dec_prep: read final h (frag) + c (row-major) -> q frag rows 2b / 2b+1.
// q frag: elem ki*8192 + qtile*512 + lane*8.
// ---------------------------------------------------------------------------
__global__ __launch_bounds__(256) void dec_prep(
    const unsigned short* __restrict__ hf_hi,
    const unsigned short* __restrict__ hf_lo,
    const float* __restrict__ c,
    unsigned short* __restrict__ qhi, unsigned short* __restrict__ qlo)
{
  int b = blockIdx.x;
  int j4 = threadIdx.x * 4;
  int ki = j4 >> 5, qq = (j4 >> 3) & 3, j8 = j4 & 7;
  size_t fh = (size_t)ki * 4096 + (b >> 4) * 512 + ((b & 15) + 16 * qq) * 8 + j8;
  ushort4 hv = *(const ushort4*)(hf_hi + fh);
  ushort4 lv = *(const ushort4*)(hf_lo + fh);
  float4 cv = *(const float4*)(c + (size_t)b * NH + j4);
  unsigned short ch[4], cl[4];
  float cf[4] = {cv.x, cv.y, cv.z, cv.w};
  #pragma unroll
  for (int k = 0; k < 4; ++k) {
    ch[k] = f2bf(cf[k]); cl[k] = f2bf(cf[k] - bf2f(ch[k]));
  }
  int rt = (2 * b) >> 4;
  int rl = ((2 * b) & 15) + 16 * qq;
  size_t fq = (size_t)ki * 8192 + rt * 512 + rl * 8 + j8;
  *(ushort4*)(qhi + fq) = hv;
  *(ushort4*)(qlo + fq) = lv;
  *(ushort4*)(qhi + fq + 8) = make_ushort4(ch[0], ch[1], ch[2], ch[3]);
  *(ushort4*)(qlo + fq + 8) = make_ushort4(cl[0], cl[1], cl[2], cl[3]);
}

// ---------------------------------------------------------------------------
// gemm_qk (frag A + frag B): grid(8,16), 256 thr, wave per 16x16 tile.
// ---------------------------------------------------------------------------
__global__ __launch_bounds__(256) void gemm_qk(
    const unsigned short* __restrict__ Ahi, const unsigned short* __restrict__ Alo,
    const unsigned short* __restrict__ Bhi, const unsigned short* __restrict__ Blo,
    float* __restrict__ C)
{
  int tid = threadIdx.x;
  int w = tid >> 6, lane = tid & 63;
  int l15 = lane & 15, q4 = (lane >> 4) * 4;
  int mtile = blockIdx.x * 2 + (w >> 1);
  int ntile = blockIdx.y * 2 + (w & 1);

  const unsigned short* Ah = Ahi + (size_t)mtile * 512 + lane * 8;
  const unsigned short* Al = Alo + (size_t)mtile * 512 + lane * 8;
  const unsigned short* Bh = Bhi + (size_t)ntile * 16384 + lane * 8;
  const unsigned short* Bl = Blo + (size_t)ntile * 16384 + lane * 8;
  f32x4 acc = {0, 0, 0, 0};
  for (int ki = 0; ki < 32; ++ki) {
    size_t ao = (size_t)ki * 8192;
    size_t bo = (size_t)ki * 512;
    bf16x8 ah = *(const bf16x8*)(Ah + ao);
    bf16x8 al = *(const bf16x8*)(Al + ao);
    bf16x8 bh = *(const bf16x8*)(Bh + bo);
    bf16x8 bl = *(const bf16x8*)(Bl + bo);
    acc = MFMA(ah, bh, acc);
    acc = MFMA(al, bh, acc);
    acc = MFMA(ah, bl, acc);
  }
  #pragma unroll
  for (int r = 0; r < 4; ++r)
    C[(size_t)(mtile * 16 + q4 + r) * 512 + ntile * 16 + l15] = acc[r];
}

// ---------------------------------------------------------------------------
// Bulk kp: kp = buf(i16, row-major) @ Wk^T (frag B, 2-term). grid(302,4).
// Wqk frag rows 256..511 are Wk -> ntile = 16 + by*4 + w.
// ---------------------------------------------------------------------------
__global__ __launch_bounds__(256) void gemm_kp(
    const short* __restrict__ A,
    const unsigned short* __restrict__ Bhi,
    const unsigned short* __restrict__ Blo,
    unsigned short* __restrict__ C)
{
  int tid = threadIdx.x;
  int w = tid >> 6, lane = tid & 63;
  int l15 = lane & 15, q8 = (lane >> 4) * 8, q4 = (lane >> 4) * 4;
  size_t m0 = (size_t)blockIdx.x * 64;
  int n0 = blockIdx.y * 64 + w * 16;
  int ntile = 16 + blockIdx.y * 4 + w;

  const unsigned short* Bh = Bhi + (size_t)ntile * 16384 + lane * 8;
  const unsigned short* Bl = Blo + (size_t)ntile * 16384 + lane * 8;
  f32x4 acc[4] = {{0,0,0,0},{0,0,0,0},{0,0,0,0},{0,0,0,0}};
  for (int ki = 0; ki < 32; ++ki) {
    int ko = ki * 32 + q8;
    size_t bo = (size_t)ki * 512;
    bf16x8 bh = *(const bf16x8*)(Bh + bo);
    bf16x8 bl = *(const bf16x8*)(Bl + bo);
    #pragma unroll
    for (int i = 0; i < 4; ++i) {
      s16x8 av = *(const s16x8*)(A + (m0 + 16 * i + l15) * (size_t)NH + ko);
      bf16x8 ah;
      #pragma unroll
      for (int k = 0; k < 8; ++k)
        ah[k] = (short)f2bf((float)av[k] * I16_INV);
      acc[i] = MFMA(ah, bh, acc[i]);
      acc[i] = MFMA(ah, bl, acc[i]);
    }
  }
  #pragma unroll
  for (int i = 0; i < 4; ++i)
    #pragma unroll
    for (int r = 0; r < 4; ++r)
      C[(m0 + 16 * i + q4 + r) * NA + n0 + l15] = f2bf(acc[i][r]);
}

// ---------------------------------------------------------------------------
// Attention: unchanged math; ctx written to Xc FRAG (A-layout, K=2048).
// ---------------------------------------------------------------------------
__global__ __launch_bounds__(256) void attn_kernel(
    const float* __restrict__ qkout,
    unsigned short* __restrict__ kp,
    const short* __restrict__ buf,
    const float* __restrict__ Wv,
    unsigned short* __restrict__ Xfhi,
    unsigned short* __restrict__ Xflo,
    int t)
{
  int b = blockIdx.x;
  int tid = threadIdx.x;
  int Mt = NL + t;
  __shared__ float sWv[256], q0[256], q1[256], kNew[256];
  __shared__ float sc[2][NM + 1];
  __shared__ float w0s[NM + 1], w1s[NM + 1];
  sWv[tid] = Wv[tid];
  q0[tid] = qkout[(size_t)(2 * b) * 512 + tid];
  q1[tid] = qkout[(size_t)(2 * b + 1) * 512 + tid];
  float kn = qkout[(size_t)(2 * b) * 512 + 256 + tid];
  kNew[tid] = kn;
  kp[((size_t)(b * NM) + (NL - 1 + t)) * NA + tid] = f2bf(kn);
  __syncthreads();

  for (int idx = tid; idx < 2 * Mt; idx += 256) {
    int m = idx >> 1, n = idx & 1;
    const float* q = n ? q1 : q0;
    float s = 0.0f;
    if (m == Mt - 1) {
      for (int a = 0; a < NA; ++a) s += tanh_f(q[a] + kNew[a]) * sWv[a];
    } else {
      const unsigned short* kpr = kp + ((size_t)(b * NM) + m) * NA;
      for (int a = 0; a < NA; a += 4) {
        ushort4 kv = *(const ushort4*)(kpr + a);
        s += tanh_f(q[a + 0] + bf2f(kv.x)) * sWv[a + 0];
        s += tanh_f(q[a + 1] + bf2f(kv.y)) * sWv[a + 1];
        s += tanh_f(q[a + 2] + bf2f(kv.z)) * sWv[a + 2];
        s += tanh_f(q[a + 3] + bf2f(kv.w)) * sWv[a + 3];
      }
    }
    sc[n][m] = s;
  }
  __syncthreads();
  for (int m = tid; m < Mt; m += 256) {
    float s0 = sc[0][m], s1 = sc[1][m];
    float mx = fmaxf(s0, s1);
    float e0 = __expf(s0 - mx), e1 = __expf(s1 - mx);
    float inv = 1.0f / (e0 + e1);
    w0s[m] = e0 * inv;
    w1s[m] = e1 * inv;
  }
  __syncthreads();

  float4 a0 = {0, 0, 0, 0}, a1 = {0, 0, 0, 0};
  const short* bb = buf + ((size_t)b * NM) * NH + tid * 4;
  for (int m = 0; m < Mt; ++m) {
    short4 v = *(const short4*)(bb + (size_t)m * NH);
    float vx = (float)v.x * I16_INV, vy = (float)v.y * I16_INV;
    float vz = (float)v.z * I16_INV, vw = (float)v.w * I16_INV;
    float w0 = w0s[m], w1 = w1s[m];
    a0.x += vx * w0; a0.y += vy * w0; a0.z += vz * w0; a0.w += vw * w0;
    a1.x += vx * w1; a1.y += vy * w1; a1.z += vz * w1; a1.w += vw * w1;
  }
  float v0[4] = {a0.x, a0.y, a0.z, a0.w};
  float v1[4] = {a1.x, a1.y, a1.z, a1.w};
  unsigned short h0[4], l0[4], h1v[4], l1v[4];
  #pragma unroll
  for (int k = 0; k < 4; ++k) {
    h0[k] = f2bf(v0[k]); l0[k] = f2bf(v0[k] - bf2f(h0[k]));
    h1v[k] = f2bf(v1[k]); l1v[k] = f2bf(v1[k] - bf2f(h1v[k]));
  }
  // frag writes: k_eff = tid*4 (n0) and 1024 + tid*4 (n1)
  int k0 = tid * 4;
  size_t fo0 = (size_t)(k0 >> 5) * 4096 + (b >> 4) * 512 +
               ((b & 15) + 16 * ((k0 >> 3) & 3)) * 8 + (k0 & 7);
  int k1 = 1024 + tid * 4;
  size_t fo1 = (size_t)(k1 >> 5) * 4096 + (b >> 4) * 512 +
               ((b & 15) + 16 * ((k1 >> 3) & 3)) * 8 + (k1 & 7);
  *(ushort4*)(Xfhi + fo0) = make_ushort4(h0[0], h0[1], h0[2], h0[3]);
  *(ushort4*)(Xflo + fo0) = make_ushort4(l0[0], l0[1], l0[2], l0[3]);
  *(ushort4*)(Xfhi + fo1) = make_ushort4(h1v[0], h1v[1], h1v[2], h1v[3]);
  *(ushort4*)(Xflo + fo1) = make_ushort4(l1v[0], l1v[1], l1v[2], l1v[3]);
}

// ---------------------------------------------------------------------------
// Decoder step (frag operands): ctx@Wdx (3-term, K=2048) + h@Wdh (3-term,
// K=1024). 512 thr; grp0 = ctx ki 0..47; grp1 = ctx ki 48..63 + h.
// ---------------------------------------------------------------------------
__global__ __launch_bounds__(512) void dec_step(
    const unsigned short* __restrict__ Xfhi,
    const unsigned short* __restrict__ Xflo,
    const unsigned short* __restrict__ qin_hi,
    const unsigned short* __restrict__ qin_lo,
    unsigned short* __restrict__ qout_hi,
    unsigned short* __restrict__ qout_lo,
    const unsigned short* __restrict__ Wdxf_hi,
    const unsigned short* __restrict__ Wdxf_lo,
    const unsigned short* __restrict__ Wdhf_hi,
    const unsigned short* __restrict__ Wdhf_lo,
    const float* __restrict__ decb,
    float* __restrict__ c,
    short* __restrict__ buf,
    const float* __restrict__ out_w, const float* __restrict__ out_b,
    float* __restrict__ out, int t)
{
  __shared__ float G[2][128][33];
  int tid = threadIdx.x;
  int w8 = tid >> 6, lane = tid & 63;
  int grp = w8 >> 2, wm = w8 & 3;
  int l15 = lane & 15, q4 = (lane >> 4) * 4;
  int bx = blockIdx.x;
  int c0 = bx * 8;

  f32x4 a00 = {0,0,0,0}, a01 = {0,0,0,0}, a10 = {0,0,0,0}, a11 = {0,0,0,0};

  // ctx phase: Wdx frag (64 ki), X frag
  {
    const unsigned short* W0h = Wdxf_hi + (size_t)(bx * 2 + 0) * 32768 + lane * 8;
    const unsigned short* W1h = Wdxf_hi + (size_t)(bx * 2 + 1) * 32768 + lane * 8;
    const unsigned short* W0l = Wdxf_lo + (size_t)(bx * 2 + 0) * 32768 + lane * 8;
    const unsigned short* W1l = Wdxf_lo + (size_t)(bx * 2 + 1) * 32768 + lane * 8;
    const unsigned short* X0h = Xfhi + (size_t)(2 * wm) * 512 + lane * 8;
    const unsigned short* X1h = Xfhi + (size_t)(2 * wm + 1) * 512 + lane * 8;
    const unsigned short* X0l = Xflo + (size_t)(2 * wm) * 512 + lane * 8;
    const unsigned short* X1l = Xflo + (size_t)(2 * wm + 1) * 512 + lane * 8;
    int klo = grp ? 48 : 0;
    int khi = grp ? 64 : 48;
    for (int ki = klo; ki < khi; ++ki) {
      size_t ao = (size_t)ki * 4096;
      size_t bo = (size_t)ki * 512;
      bf16x8 x0h = *(const bf16x8*)(X0h + ao);
      bf16x8 x0l = *(const bf16x8*)(X0l + ao);
      bf16x8 x1h = *(const bf16x8*)(X1h + ao);
      bf16x8 x1l = *(const bf16x8*)(X1l + ao);
      bf16x8 y0h = *(const bf16x8*)(W0h + bo);
      bf16x8 y0l = *(const bf16x8*)(W0l + bo);
      bf16x8 y1h = *(const bf16x8*)(W1h + bo);
      bf16x8 y1l = *(const bf16x8*)(W1l + bo);
      a00 = MFMA(x0h, y0h, a00); a00 = MFMA(x0l, y0h, a00); a00 = MFMA(x0h, y0l, a00);
      a01 = MFMA(x0h, y1h, a01); a01 = MFMA(x0l, y1h, a01); a01 = MFMA(x0h, y1l, a01);
      a10 = MFMA(x1h, y0h, a10); a10 = MFMA(x1l, y0h, a10); a10 = MFMA(x1h, y0l, a10);
      a11 = MFMA(x1h, y1h, a11); a11 = MFMA(x1l, y1h, a11); a11 = MFMA(x1h, y1l, a11);
    }
  }
  // h phase (grp1): A from q frag (even rows), B = Wdh frag
  if (grp) {
    int qt0 = 4 * wm + (l15 >> 3);
    int ln = 2 * (l15 & 7) + 16 * (lane >> 4);
    const unsigned short* A0h = qin_hi + (size_t)qt0 * 512 + ln * 8;
    const unsigned short* A0l = qin_lo + (size_t)qt0 * 512 + ln * 8;
    const unsigned short* A1h = qin_hi + (size_t)(qt0 + 2) * 512 + ln * 8;
    const unsigned short* A1l = qin_lo + (size_t)(qt0 + 2) * 512 + ln * 8;
    const unsigned short* B0h = Wdhf_hi + (size_t)(bx * 2 + 0) * 16384 + lane * 8;
    const unsigned short* B1h = Wdhf_hi + (size_t)(bx * 2 + 1) * 16384 + lane * 8;
    const unsigned short* B0l = Wdhf_lo + (size_t)(bx * 2 + 0) * 16384 + lane * 8;
    const unsigned short* B1l = Wdhf_lo + (size_t)(bx * 2 + 1) * 16384 + lane * 8;
    for (int ki = 0; ki < 32; ++ki) {
      size_t ao = (size_t)ki * 8192;
      size_t bo = (size_t)ki * 512;
      bf16x8 x0h = *(const bf16x8*)(A0h + ao);
      bf16x8 x0l = *(const bf16x8*)(A0l + ao);
      bf16x8 x1h = *(const bf16x8*)(A1h + ao);
      bf16x8 x1l = *(const bf16x8*)(A1l + ao);
      bf16x8 y0h = *(const bf16x8*)(B0h + bo);
      bf16x8 y0l = *(const bf16x8*)(B0l + bo);
      bf16x8 y1h = *(const bf16x8*)(B1h + bo);
      bf16x8 y1l = *(const bf16x8*)(B1l + bo);
      a00 = MFMA(x0h, y0h, a00); a00 = MFMA(x0l, y0h, a00); a00 = MFMA(x0h, y0l, a00);
      a01 = MFMA(x0h, y1h, a01); a01 = MFMA(x0l, y1h, a01); a01 = MFMA(x0h, y1l, a01);
      a10 = MFMA(x1h, y0h, a10); a10 = MFMA(x1l, y0h, a10); a10 = MFMA(x1h, y0l, a10);
      a11 = MFMA(x1h, y1h, a11); a11 = MFMA(x1l, y1h, a11); a11 = MFMA(x1h, y1l, a11);
    }
  }
  #pragma unroll
  for (int r = 0; r < 4; ++r) {
    G[grp][32 * wm + q4 + r][l15]           = a00[r];
    G[grp][32 * wm + q4 + r][16 + l15]      = a01[r];
    G[grp][32 * wm + 16 + q4 + r][l15]      = a10[r];
    G[grp][32 * wm + 16 + q4 + r][16 + l15] = a11[r];
  }
  __syncthreads();

  if (tid < 256) {
    int b = tid >> 1;
    int kc = c0 + (tid & 1) * 4;
    int cc0 = (tid & 1) * 4;
    float4 cold = *(const float4*)(c + (size_t)b * NH + kc);
    float rc[4], rh[4];
    #pragma unroll
    for (int j = 0; j < 4; ++j) {
      int cc = cc0 + j;
      float gate[4];
      #pragma unroll
      for (int q = 0; q < 4; ++q) {
        int gi = q * 8 + cc;
        gate[q] = G[0][b][gi] + G[1][b][gi] + decb[q * NH + kc + j];
      }
      float co = (&cold.x)[j];
      float cn = sig_f(gate[1]) * co + sig_f(gate[0]) * tanh_f(gate[2]);
      float hn = sig_f(gate[3]) * tanh_f(cn);
      rc[j] = cn; rh[j] = hn;
    }
    *(float4*)(c + (size_t)b * NH + kc) = make_float4(rc[0], rc[1], rc[2], rc[3]);

    float py = 0.0f;
    #pragma unroll
    for (int j = 0; j < 4; ++j) py += rh[j] * out_w[kc + j];
    if (blockIdx.x == 0 && (tid & 1) == 0) py += out_b[0];
    py += __shfl_down(py, 1);
    if ((tid & 1) == 0) atomicAdd(&out[b * NT + t], py);

    if (t < NT - 1) {
      unsigned short hh[4], hl[4], ch[4], cl[4];
      short hq[4];
      #pragma unroll
      for (int j = 0; j < 4; ++j) {
        hh[j] = f2bf(rh[j]); hl[j] = f2bf(rh[j] - bf2f(hh[j]));
        ch[j] = f2bf(rc[j]); cl[j] = f2bf(rc[j] - bf2f(ch[j]));
        hq[j] = f2i16(rh[j]);
      }
      *(short4*)(buf + (size_t)(b * NM + NL + t) * NH + kc) =
          make_short4(hq[0], hq[1], hq[2], hq[3]);
      // q frag writes: rows 2b (h) and 2b+1 (c)
      int ki = kc >> 5, qq = (kc >> 3) & 3, j8 = kc & 7;
      int rt = (2 * b) >> 4;
      int rl = ((2 * b) & 15) + 16 * qq;
      size_t fq = (size_t)ki * 8192 + rt * 512 + rl * 8 + j8;
      *(ushort4*)(qout_hi + fq) = make_ushort4(hh[0], hh[1], hh[2], hh[3]);
      *(ushort4*)(qout_lo + fq) = make_ushort4(hl[0], hl[1], hl[2], hl[3]);
      *(ushort4*)(qout_hi + fq + 8) = make_ushort4(ch[0], ch[1], ch[2], ch[3]);
      *(ushort4*)(qout_lo + fq + 8) = make_ushort4(cl[0], cl[1], cl[2], cl[3]);
    }
  }
}

// ---------------------------------------------------------------------------
extern "C" void kernel_launch(void* const* d_in, const int* in_sizes, int n_in,
                              void* d_out, int out_size, void* d_ws, size_t ws_size,
                              hipStream_t stream) {
  const float* x       = (const float*)d_in[0];
  const float* conv1_w = (const float*)d_in[1];
  const float* conv1_b = (const float*)d_in[2];
  const float* conv2_w = (const float*)d_in[3];
  const float* conv2_b = (const float*)d_in[4];
  const float* lin3_w  = (const float*)d_in[5];
  const float* lin3_b  = (const float*)d_in[6];
  const float* enc_Wih = (const float*)d_in[7];
  const float* enc_Whh = (const float*)d_in[8];
  const float* enc_b   = (const float*)d_in[9];
  const float* attn_Wq = (const float*)d_in[10];
  const float* attn_Wk = (const float*)d_in[11];
  const float* attn_Wv = (const float*)d_in[12];
  const float* dec_Wih = (const float*)d_in[13];
  const float* dec_Whh = (const float*)d_in[14];
  const float* dec_b   = (const float*)d_in[15];
  const float* out_w   = (const float*)d_in[16];
  const float* out_b   = (const float*)d_in[17];
  float* out = (float*)d_out;

  // ---- workspace carve: 106,102,784 B (same totals as rounds 6-8) ----
  unsigned short* W = (unsigned short*)d_ws;
  short*          buf    = (short*)W;                  // 19,791,872 i16
  unsigned short* kp     = W + (size_t)19791872;       // 4,947,968
  unsigned short* qA_hi  = kp + 4947968;               // 262,144 (q frag)
  unsigned short* qA_lo  = qA_hi + 262144;
  unsigned short* qB_hi  = qA_lo + 262144;
  unsigned short* qB_lo  = qB_hi + 262144;
  unsigned short* Xf_hi  = qB_lo + 262144;             // 262,144 (ctx frag)
  unsigned short* Xf_lo  = Xf_hi + 262144;
  unsigned short* Wqkf_hi = Xf_lo + 262144;            // 524,288 (frag)
  unsigned short* Wqkf_lo = Wqkf_hi + 524288;
  unsigned short* Wdhf_hi = Wqkf_lo + 524288;          // 4,194,304 (enc Whh first)
  unsigned short* Wdhf_lo = Wdhf_hi + 4194304;
  unsigned short* Wdxf_hi = Wdhf_lo + 4194304;         // 8,388,608
  unsigned short* Wdxf_lo = Wdxf_hi + 8388608;         // 8,388,608
  float* c     = (float*)(Wdxf_lo + 8388608);          // 131,072 f
  float* qkout = c + 131072;                           // 131,072 f
  // encoder-phase overlays in Wdxf regions (dead until dec weight transform):
  unsigned short* hfA_hi = Wdxf_hi;                    // 131,072 (h frag)
  unsigned short* hfA_lo = Wdxf_hi + 131072;
  unsigned short* hfB_hi = Wdxf_hi + 262144;
  unsigned short* hfB_lo = Wdxf_hi + 393216;
  unsigned short* xsf_hi = Wdxf_hi + 524288;           // 524,288
  unsigned short* xsf_lo = xsf_hi + 524288;            // 524,288
  unsigned short* Wxf_hi = xsf_lo + 524288;            // 131,072
  unsigned short* Wxf_lo = Wxf_hi + 131072;            // 131,072
  float* lstm_in = (float*)Wdxf_lo;                    // 294,912 f

  init_all<<<512, 256, 0, stream>>>(c, hfA_hi, hfA_lo, out);
  conv_front<<<NB, 128, 0, stream>>>(x, conv1_w, conv1_b, conv2_w, conv2_b,
                                     lin3_w, lin3_b, lstm_in);
  frag_xs<<<256, 256, 0, stream>>>(lstm_in, xsf_hi, xsf_lo);
  frag_wx<<<64, 256, 0, stream>>>(enc_Wih, Wxf_hi, Wxf_lo);
  frag_w<<<2048, 256, 0, stream>>>(enc_Whh, 1024, 5, Wdhf_hi, Wdhf_lo, 524288);
  frag_wqk<<<256, 256, 0, stream>>>(attn_Wq, attn_Wk, Wqkf_hi, Wqkf_lo);

  // Encoder: 128 per-step launches, h frag ping-pong
  for (int t = 0; t < NL; ++t) {
    const unsigned short* ih = (t & 1) ? hfB_hi : hfA_hi;
    const unsigned short* il = (t & 1) ? hfB_lo : hfA_lo;
    unsigned short* oh = (t & 1) ? hfA_hi : hfB_hi;
    unsigned short* ol = (t & 1) ? hfA_lo : hfB_lo;
    enc_step<<<128, 512, 0, stream>>>(ih, il, oh, ol, Wdhf_hi, Wdhf_lo,
                                      Wxf_hi, Wxf_lo, xsf_hi, xsf_lo,
                                      enc_b, c, buf, t);
  }
  // t=127 (odd) wrote hfA -> final h there

  dec_prep<<<NB, 256, 0, stream>>>(hfA_hi, hfA_lo, c, qA_hi, qA_lo);
  gemm_kp<<<dim3(302, 4), 256, 0, stream>>>(buf, Wqkf_hi, Wqkf_lo, kp);

  // decoder weight transforms (overwrite encoder overlays)
  frag_w<<<4096, 256, 0, stream>>>(dec_Wih, 2048, 6, Wdxf_hi, Wdxf_lo, 1048576);
  frag_w<<<2048, 256, 0, stream>>>(dec_Whh, 1024, 5, Wdhf_hi, Wdhf_lo, 524288);

  for (int t = 0; t < NT; ++t) {
    const unsigned short* qih = (t & 1) ? qB_hi : qA_hi;
    const unsigned short* qil = (t & 1) ? qB_lo : qA_lo;
    unsigned short* qoh = (t & 1) ? qA_hi : qB_hi;
    unsigned short* qol = (t & 1) ? qA_lo : qB_lo;
    gemm_qk<<<dim3(8, 16), 256, 0, stream>>>(qih, qil, Wqkf_hi, Wqkf_lo, qkout);
    attn_kernel<<<NB, 256, 0, stream>>>(qkout, kp, buf, attn_Wv, Xf_hi, Xf_lo, t);
    dec_step<<<128, 512, 0, stream>>>(Xf_hi, Xf_lo, qih, qil, qoh, qol,
                                      Wdxf_hi, Wdxf_lo, Wdhf_hi, Wdhf_lo,
                                      dec_b, c, buf, out_w, out_b, out, t);
  }
}